// Round 1
// 1429.872 us; speedup vs baseline: 1.1374x; 1.1374x over previous
//
#include <hip/hip_runtime.h>

#define NN 200000
#define NEDGE 1000000
#define TOT (2*NN)
#define NBLK 391           // ceil(400000/1024)
#define PTILES 3125        // 200000 / 64, exact

typedef __attribute__((ext_vector_type(8))) short short8;
typedef __attribute__((ext_vector_type(4))) float floatx4;

__device__ inline float bf2f(unsigned int u) {
    unsigned int x = (u & 0xffffu) << 16;
    return __builtin_bit_cast(float, x);
}
__device__ inline unsigned int f2bf(float f) {
    unsigned int x = __builtin_bit_cast(unsigned int, f);
    x += 0x7fffu + ((x >> 16) & 1u);
    return (x >> 16) & 0xffffu;
}
__device__ inline short8 cvt8(float4 v0, float4 v1) {
    short8 r;
    r[0]=(short)f2bf(v0.x); r[1]=(short)f2bf(v0.y); r[2]=(short)f2bf(v0.z); r[3]=(short)f2bf(v0.w);
    r[4]=(short)f2bf(v1.x); r[5]=(short)f2bf(v1.y); r[6]=(short)f2bf(v1.z); r[7]=(short)f2bf(v1.w);
    return r;
}

// ---------------- phase 0: fold weights (fp32 in -> bf16 [o][i]) ----------
// Wt slots per node type t: 0=Wk raw, 1=Wm raw, 2=Wq@watt[1-t]^T, 3=BD(wmsg[1-t]), 4=Wa
__global__ void k_weights(const float* Wk, const float* bk, const float* Wq, const float* bq,
                          const float* Wm, const float* bm, const float* Wa, const float* ba,
                          const float* watt, const float* wmsg,
                          unsigned short* Wt, float* beff) {
    int t = blockIdx.x / 5, p = blockIdx.x % 5;
    int te = 1 - t;   // edge type feeding node type t as destination
    unsigned short* dstW = Wt + (size_t)(t*5+p)*16384;
    float* dstB = beff + (t*5+p)*128;
    for (int idx = threadIdx.x; idx < 16384; idx += blockDim.x) {
        int o = idx >> 7, i = idx & 127;
        float v;
        if (p == 0)      v = Wk[(t*128+i)*128 + o];
        else if (p == 1) v = Wm[(t*128+i)*128 + o];
        else if (p == 2) {      // Wq_eff[i][h*32+d] = sum_f Wq[i][h*32+f]*watt[te][h][d][f]
            int h = o >> 5, d = o & 31;
            float s = 0.f;
            for (int f = 0; f < 32; ++f)
                s += Wq[(t*128+i)*128 + h*32 + f] * watt[((te*4+h)*32+d)*32 + f];
            v = s;
        } else if (p == 3) {    // block-diag wmsg: y[h*32+f] = sum_d in[h*32+d]*wmsg[te][h][d][f]
            int ho = o >> 5, f = o & 31, hi = i >> 5, d = i & 31;
            v = (ho == hi) ? wmsg[((te*4+ho)*32+d)*32 + f] : 0.f;
        } else            v = Wa[(t*128+i)*128 + o];
        dstW[o*128 + i] = (unsigned short)f2bf(v);
    }
    for (int o = threadIdx.x; o < 128; o += blockDim.x) {
        float v;
        if (p == 0)      v = bk[t*128+o];
        else if (p == 1) v = bm[t*128+o];
        else if (p == 2) {
            int h = o >> 5, d = o & 31;
            float s = 0.f;
            for (int f = 0; f < 32; ++f)
                s += bq[t*128 + h*32 + f] * watt[((te*4+h)*32+d)*32 + f];
            v = s;
        } else if (p == 3) v = 0.f;
        else              v = ba[t*128+o];
        dstB[o] = v;
    }
}

// ---------------- CSR build ------------------------------------------------
__global__ void k_hist(const int* ei, int* deg) {
    int f = blockIdx.x*blockDim.x + threadIdx.x;
    if (f >= 2*NEDGE) return;
    int t = f / NEDGE, e = f - t*NEDGE;
    int dst = ei[(t*2+1)*NEDGE + e];
    atomicAdd(&deg[(1-t)*NN + dst], 1);
}

__global__ void k_scan1(const int* deg, int* offs, int* bsum) {
    __shared__ int sd[1024];
    int tid = threadIdx.x;
    int i = blockIdx.x*1024 + tid;
    int v = (i < TOT) ? deg[i] : 0;
    sd[tid] = v; __syncthreads();
    for (int o = 1; o < 1024; o <<= 1) {
        int tv = 0;
        if (tid >= o) tv = sd[tid - o];
        __syncthreads();
        if (tid >= o) sd[tid] += tv;
        __syncthreads();
    }
    if (i < TOT) offs[i] = sd[tid] - v;
    if (tid == 1023) bsum[blockIdx.x] = sd[tid];
}

__global__ void k_scan2(int* bsum) {
    __shared__ int sd[512];
    int tid = threadIdx.x;
    int v = (tid < NBLK) ? bsum[tid] : 0;
    sd[tid] = v; __syncthreads();
    for (int o = 1; o < 512; o <<= 1) {
        int tv = 0;
        if (tid >= o) tv = sd[tid - o];
        __syncthreads();
        if (tid >= o) sd[tid] += tv;
        __syncthreads();
    }
    if (tid < NBLK) bsum[tid] = sd[tid] - v;
}

__global__ void k_scan3(int* offs, const int* bsum, int* cursor) {
    int i = blockIdx.x*blockDim.x + threadIdx.x;
    if (i >= TOT) return;
    int v = offs[i] + bsum[i >> 10];
    offs[i] = v;
    cursor[i] = v;
}

__global__ void k_scatter(const int* ei, int* cursor, int* slot) {
    int f = blockIdx.x*blockDim.x + threadIdx.x;
    if (f >= 2*NEDGE) return;
    int t = f / NEDGE, e = f - t*NEDGE;
    int src = ei[(t*2+0)*NEDGE + e];
    int dst = ei[(t*2+1)*NEDGE + e];
    int pos = atomicAdd(&cursor[(1-t)*NN + dst], 1);
    slot[pos] = src;
}

// stage a 128x128 bf16 weight matrix: global (linear) -> regs -> LDS (pad 136)
#define STAGE_LOAD(reg, p) \
    { const unsigned short* wsrc_ = Wt + (size_t)(t*5+(p))*16384; \
      _Pragma("unroll") \
      for (int it_ = 0; it_ < 8; ++it_) \
          reg[it_] = *(const uint4*)(wsrc_ + (it_*256+tid)*8); }

#define STAGE_WRITE(reg) \
    { _Pragma("unroll") \
      for (int it_ = 0; it_ < 8; ++it_) { int e_ = (it_*256+tid)*8; \
          *(uint4*)(ws + (e_>>7)*136 + (e_&127)) = reg[it_]; } }

// ---------------- phase 1: projections (MFMA GEMM) -------------------------
// 64-row tile, 4 waves x 16 rows. A-frags straight from global (no x LDS tile).
// K computed then held packed bf16; M computed; K|M stored packed 4B single-pass.
// Q (pre-transformed) stored fp32 into Qo (= out buffer).
__global__ __launch_bounds__(256, 3) void k_proj(const float* x, const unsigned short* Wt,
        const float* beff, unsigned short* KM, float* Qo) {
    __shared__ __align__(16) unsigned short ws[128*136];
    int t = blockIdx.y;
    int tid = threadIdx.x;
    int wave = tid >> 6, lane = tid & 63;
    int lrow = lane & 15, quad = lane >> 4;
    int rowbase = blockIdx.x * 64;
    int row = rowbase + wave*16 + lrow;          // A-frag row (always < NN: 3125*64 = NN)
    const float* xr = x + (size_t)t*NN*128 + (size_t)row*128 + quad*8;

    // issue x loads (HBM) first, then weight loads (L2) — all in flight together
    float4 xv[8];
#pragma unroll
    for (int ks = 0; ks < 4; ++ks) {
        xv[2*ks]   = *(const float4*)(xr + ks*32);
        xv[2*ks+1] = *(const float4*)(xr + ks*32 + 4);
    }
    uint4 wreg[8];
    STAGE_LOAD(wreg, 0);                         // Wk
    short8 a[4];
#pragma unroll
    for (int ks = 0; ks < 4; ++ks) a[ks] = cvt8(xv[2*ks], xv[2*ks+1]);
    STAGE_WRITE(wreg);
    __syncthreads();

    // ---- K GEMM (prefetch Wm during) ----
    uint4 wreg2[8];
    STAGE_LOAD(wreg2, 1);                        // Wm
    floatx4 acc[8];
#pragma unroll
    for (int j = 0; j < 8; ++j) acc[j] = (floatx4){0.f,0.f,0.f,0.f};
#pragma unroll
    for (int ks = 0; ks < 4; ++ks) {
        int koff = ks*32 + quad*8;
#pragma unroll
        for (int j = 0; j < 8; ++j) {
            short8 b = *(const short8*)(ws + (j*16 + lrow)*136 + koff);
            acc[j] = __builtin_amdgcn_mfma_f32_16x16x32_bf16(a[ks], b, acc[j], 0, 0, 0);
        }
    }
    const float* bkb = beff + (t*5+0)*128;
    unsigned int kb[8][2];                       // K results held packed bf16
#pragma unroll
    for (int j = 0; j < 8; ++j) {
        float bias = bkb[j*16 + lrow];
        kb[j][0] = f2bf(acc[j][0]+bias) | (f2bf(acc[j][1]+bias) << 16);
        kb[j][1] = f2bf(acc[j][2]+bias) | (f2bf(acc[j][3]+bias) << 16);
    }
    __syncthreads();                             // all waves done reading Wk
    STAGE_WRITE(wreg2);
    __syncthreads();

    // ---- M GEMM (prefetch Wq during), then single-pass packed K|M store ----
    STAGE_LOAD(wreg, 2);                         // Wq_eff
#pragma unroll
    for (int j = 0; j < 8; ++j) acc[j] = (floatx4){0.f,0.f,0.f,0.f};
#pragma unroll
    for (int ks = 0; ks < 4; ++ks) {
        int koff = ks*32 + quad*8;
#pragma unroll
        for (int j = 0; j < 8; ++j) {
            short8 b = *(const short8*)(ws + (j*16 + lrow)*136 + koff);
            acc[j] = __builtin_amdgcn_mfma_f32_16x16x32_bf16(a[ks], b, acc[j], 0, 0, 0);
        }
    }
    const float* bmb = beff + (t*5+1)*128;
    unsigned short* KMb = KM + (size_t)t*NN*256;
    int orow = rowbase + wave*16 + quad*4;       // C-frag rows (quad*4 + r)
#pragma unroll
    for (int j = 0; j < 8; ++j) {
        int col = j*16 + lrow;
        float bias = bmb[col];
        unsigned int k01 = kb[j][0], k23 = kb[j][1];
        *(unsigned int*)(KMb + (size_t)(orow+0)*256 + col*2) = (k01 & 0xffffu) | (f2bf(acc[j][0]+bias) << 16);
        *(unsigned int*)(KMb + (size_t)(orow+1)*256 + col*2) = (k01 >> 16)     | (f2bf(acc[j][1]+bias) << 16);
        *(unsigned int*)(KMb + (size_t)(orow+2)*256 + col*2) = (k23 & 0xffffu) | (f2bf(acc[j][2]+bias) << 16);
        *(unsigned int*)(KMb + (size_t)(orow+3)*256 + col*2) = (k23 >> 16)     | (f2bf(acc[j][3]+bias) << 16);
    }
    __syncthreads();                             // all waves done reading Wm
    STAGE_WRITE(wreg);
    __syncthreads();

    // ---- Q GEMM ----
#pragma unroll
    for (int j = 0; j < 8; ++j) acc[j] = (floatx4){0.f,0.f,0.f,0.f};
#pragma unroll
    for (int ks = 0; ks < 4; ++ks) {
        int koff = ks*32 + quad*8;
#pragma unroll
        for (int j = 0; j < 8; ++j) {
            short8 b = *(const short8*)(ws + (j*16 + lrow)*136 + koff);
            acc[j] = __builtin_amdgcn_mfma_f32_16x16x32_bf16(a[ks], b, acc[j], 0, 0, 0);
        }
    }
    const float* bqb = beff + (t*5+2)*128;
    float* Qb = Qo + (size_t)t*NN*128;
#pragma unroll
    for (int j = 0; j < 8; ++j) {
        int col = j*16 + lrow;
        float bias = bqb[col];
#pragma unroll
        for (int r = 0; r < 4; ++r)
            Qb[(size_t)(orow+r)*128 + col] = acc[j][r] + bias;
    }
}

// ---------------- phase 3: gather + online softmax + aggregate -------------
// reads Qtr (fp32) from QA, writes raw aggregate of M (fp32) in place
__global__ __launch_bounds__(256) void k_gather(const unsigned short* KM, float* QA,
        const int* offs, const int* deg, const int* slot, const float* mu) {
    int nt = blockIdx.y;
    int grp = threadIdx.x >> 5, ln = threadIdx.x & 31;
    int node = blockIdx.x*8 + grp;
    int s = 1 - nt;                 // edge type == src node type
    int head = ln >> 3;
    float* qptr = QA + ((size_t)nt*NN + node)*128 + ln*4;
    float4 q = *(const float4*)qptr;
    float mf = mu[s*4 + head] * 0.17677669529663687f;   // mu[t_edge,h] / sqrt(DK)
    float q0 = q.x*mf, q1 = q.y*mf, q2 = q.z*mf, q3 = q.w*mf;
    int g = nt*NN + node;
    int st = offs[g], en = st + deg[g];
    const unsigned short* KMb = KM + (size_t)s*NN*256;
    float m = -INFINITY, l = 0.f;
    float a0=0.f, a1=0.f, a2=0.f, a3=0.f;
    for (int e = st; e < en; ++e) {
        int src = slot[e];
        uint4 km = *(const uint4*)(KMb + (size_t)src*256 + ln*8);
        float k0 = bf2f(km.x), m0 = bf2f(km.x>>16);
        float k1 = bf2f(km.y), m1 = bf2f(km.y>>16);
        float k2 = bf2f(km.z), m2 = bf2f(km.z>>16);
        float k3 = bf2f(km.w), m3 = bf2f(km.w>>16);
        float dot = k0*q0 + k1*q1 + k2*q2 + k3*q3;
        dot += __shfl_xor(dot, 1);
        dot += __shfl_xor(dot, 2);
        dot += __shfl_xor(dot, 4);
        float nm = fmaxf(m, dot);
        float pp = __expf(dot - nm);
        float sc = __expf(m - nm);
        l = l*sc + pp;
        m = nm;
        a0 = a0*sc + pp*m0;
        a1 = a1*sc + pp*m1;
        a2 = a2*sc + pp*m2;
        a3 = a3*sc + pp*m3;
    }
    if (l > 0.f) { float inv = 1.f/l; a0*=inv; a1*=inv; a2*=inv; a3*=inv; }
    *(float4*)qptr = make_float4(a0, a1, a2, a3);
}

// ---------------- phase 4: aggM @ BD(wmsg) -> gelu -> @Wa -> skip+LN -------
// 64-row tile, A-frags of the aggregate straight from global; gelu intermediate
// bounced through a 64-row LDS buffer; Wa prefetched during GEMM1.
__global__ __launch_bounds__(256, 3) void k_epilogue(const float* x, const unsigned short* Wt,
        const float* beff, const float* skipv, const float* lns, const float* lnb, float* out) {
    __shared__ __align__(16) unsigned short ws[128*136];
    __shared__ __align__(16) unsigned short gs[64*136];
    int t = blockIdx.y;
    int tid = threadIdx.x;
    int wave = tid >> 6, lane = tid & 63;
    int lrow = lane & 15, quad = lane >> 4;
    int rowbase = blockIdx.x * 64;
    int row = rowbase + wave*16 + lrow;
    float* Ob = out + (size_t)t*NN*128;

    const float* ar = Ob + (size_t)row*128 + quad*8;
    float4 xv[8];
#pragma unroll
    for (int ks = 0; ks < 4; ++ks) {
        xv[2*ks]   = *(const float4*)(ar + ks*32);
        xv[2*ks+1] = *(const float4*)(ar + ks*32 + 4);
    }
    uint4 wreg[8];
    STAGE_LOAD(wreg, 3);                         // BD(wmsg)
    short8 a[4];
#pragma unroll
    for (int ks = 0; ks < 4; ++ks) a[ks] = cvt8(xv[2*ks], xv[2*ks+1]);
    STAGE_WRITE(wreg);
    __syncthreads();

    // ---- GEMM1: agg @ BD(wmsg)  (prefetch Wa during) ----
    uint4 wreg2[8];
    STAGE_LOAD(wreg2, 4);                        // Wa
    floatx4 acc[8];
#pragma unroll
    for (int j = 0; j < 8; ++j) acc[j] = (floatx4){0.f,0.f,0.f,0.f};
#pragma unroll
    for (int ks = 0; ks < 4; ++ks) {
        int koff = ks*32 + quad*8;
#pragma unroll
        for (int j = 0; j < 8; ++j) {
            short8 b = *(const short8*)(ws + (j*16 + lrow)*136 + koff);
            acc[j] = __builtin_amdgcn_mfma_f32_16x16x32_bf16(a[ks], b, acc[j], 0, 0, 0);
        }
    }
    // gelu -> gs (bf16)
#pragma unroll
    for (int j = 0; j < 8; ++j) {
        int col = j*16 + lrow;
#pragma unroll
        for (int r = 0; r < 4; ++r) {
            int rl = wave*16 + quad*4 + r;
            float v = acc[j][r];
            v = 0.5f*v*(1.f + erff(v*0.70710678118654752f));
            gs[rl*136 + col] = (unsigned short)f2bf(v);
        }
    }
    __syncthreads();                             // ws consumed AND gs complete
    STAGE_WRITE(wreg2);
    __syncthreads();

    // ---- GEMM2: gelu @ Wa ----
    short8 a2[4];
#pragma unroll
    for (int ks = 0; ks < 4; ++ks)
        a2[ks] = *(const short8*)(gs + (wave*16 + lrow)*136 + ks*32 + quad*8);
#pragma unroll
    for (int j = 0; j < 8; ++j) acc[j] = (floatx4){0.f,0.f,0.f,0.f};
#pragma unroll
    for (int ks = 0; ks < 4; ++ks) {
        int koff = ks*32 + quad*8;
#pragma unroll
        for (int j = 0; j < 8; ++j) {
            short8 b = *(const short8*)(ws + (j*16 + lrow)*136 + koff);
            acc[j] = __builtin_amdgcn_mfma_f32_16x16x32_bf16(a2[ks], b, acc[j], 0, 0, 0);
        }
    }

    // ---- skip + LayerNorm (reduced across the 16 lanes sharing a row) ----
    const float* bb = beff + (t*5+4)*128;
    float alpha = 1.f/(1.f + __expf(-skipv[t]));
    float beta = 1.f - alpha;
    const float* xb = x + (size_t)t*NN*128;
#pragma unroll
    for (int r = 0; r < 4; ++r) {
        int orow = rowbase + wave*16 + quad*4 + r;
        float o[8]; float sum = 0.f, ss = 0.f;
#pragma unroll
        for (int j = 0; j < 8; ++j) {
            int col = j*16 + lrow;
            float xvv = xb[(size_t)orow*128 + col];
            float v = alpha*(acc[j][r] + bb[col]) + beta*xvv;
            o[j] = v; sum += v; ss += v*v;
        }
        sum += __shfl_xor(sum, 1); sum += __shfl_xor(sum, 2);
        sum += __shfl_xor(sum, 4); sum += __shfl_xor(sum, 8);
        ss  += __shfl_xor(ss, 1);  ss  += __shfl_xor(ss, 2);
        ss  += __shfl_xor(ss, 4);  ss  += __shfl_xor(ss, 8);
        float mean = sum * (1.f/128.f);
        float var = fmaxf(ss * (1.f/128.f) - mean*mean, 0.f);
        float rstd = rsqrtf(var + 1e-5f);
#pragma unroll
        for (int j = 0; j < 8; ++j) {
            int col = j*16 + lrow;
            Ob[(size_t)orow*128 + col] = (o[j]-mean)*rstd*lns[t*128+col] + lnb[t*128+col];
        }
    }
}

// ---------------- launch ---------------------------------------------------
extern "C" void kernel_launch(void* const* d_in, const int* in_sizes, int n_in,
                              void* d_out, int out_size, void* d_ws, size_t ws_size,
                              hipStream_t stream) {
    const float* x    = (const float*)d_in[0];
    const int*   ei   = (const int*)d_in[1];
    const float* Wk   = (const float*)d_in[2];
    const float* bk   = (const float*)d_in[3];
    const float* Wq   = (const float*)d_in[4];
    const float* bq   = (const float*)d_in[5];
    const float* Wm   = (const float*)d_in[6];
    const float* bm   = (const float*)d_in[7];
    const float* Wa   = (const float*)d_in[8];
    const float* ba   = (const float*)d_in[9];
    const float* watt = (const float*)d_in[10];
    const float* wmsg = (const float*)d_in[11];
    const float* mu   = (const float*)d_in[12];
    const float* skp  = (const float*)d_in[13];
    const float* lns  = (const float*)d_in[14];
    const float* lnb  = (const float*)d_in[15];
    float* out = (float*)d_out;

    char* w = (char*)d_ws;
    unsigned short* Wt = (unsigned short*)(w + 0);         //   327,680 B
    float* beff        = (float*)(w + 327680);             //     5,120 B
    int* deg           = (int*)(w + 332800);               // 1,600,000 B
    int* offs          = (int*)(w + 1932800);              // 1,600,000 B
    int* cursor        = (int*)(w + 3532800);              // 1,600,000 B
    int* bsum          = (int*)(w + 5132800);              //     4,096 B
    int* slot          = (int*)(w + 5136896);              // 8,000,000 B
    unsigned short* KM = (unsigned short*)(w + 13136896);  // 204,800,000 B -> 217,936,896 total

    hipMemsetAsync(deg, 0, (size_t)TOT*4, stream);
    k_weights<<<10, 256, 0, stream>>>(Wk,bk,Wq,bq,Wm,bm,Wa,ba,watt,wmsg,Wt,beff);
    k_hist<<<(2*NEDGE+255)/256, 256, 0, stream>>>(ei, deg);
    k_scan1<<<NBLK, 1024, 0, stream>>>(deg, offs, bsum);
    k_scan2<<<1, 512, 0, stream>>>(bsum);
    k_scan3<<<(TOT+255)/256, 256, 0, stream>>>(offs, bsum, cursor);
    k_scatter<<<(2*NEDGE+255)/256, 256, 0, stream>>>(ei, cursor, slot);
    k_proj<<<dim3(PTILES,2), 256, 0, stream>>>(x, Wt, beff, KM, out);
    k_gather<<<dim3(NN/8,2), 256, 0, stream>>>(KM, out, offs, deg, slot, mu);
    k_epilogue<<<dim3(PTILES,2), 256, 0, stream>>>(x, Wt, beff, skp, lns, lnb, out);
}